// Round 12
// baseline (538.074 us; speedup 1.0000x reference)
//
#include <hip/hip_runtime.h>
#include <stdint.h>

typedef __bf16 bf16;
typedef __attribute__((ext_vector_type(2))) __bf16 bf16x2;
typedef __attribute__((ext_vector_type(4))) __bf16 bf16x4;
typedef __attribute__((ext_vector_type(8))) __bf16 bf16x8;
typedef __attribute__((ext_vector_type(4))) float f32x4;
typedef __attribute__((ext_vector_type(4))) short s16x4;

#define B_  2
#define S_  2048
#define H_  1024
#define NH_ 16
#define HD_ 64

// async 16B global->LDS. LDS dest = wave-uniform base + lane*16.
__device__ __forceinline__ void glds16(const bf16* g, bf16* l) {
  __builtin_amdgcn_global_load_lds(
      (const __attribute__((address_space(1))) uint32_t*)g,
      (__attribute__((address_space(3))) uint32_t*)l, 16, 0, 0);
}

// PV MFMA: 16x16x16 bf16 — B operand layout (k=quad*4+e, col=l15) matches the
// S^T MFMA D layout exactly, so softmax P registers feed it with NO relayout.
__device__ __forceinline__ f32x4 pv_mfma(bf16x4 a, bf16x4 b, f32x4 c) {
#if __has_builtin(__builtin_amdgcn_mfma_f32_16x16x16bf16_1k)
  union U { bf16x4 h; s16x4 s; };
  U ua; ua.h = a;
  U ub; ub.h = b;
  return __builtin_amdgcn_mfma_f32_16x16x16bf16_1k(ua.s, ub.s, c, 0, 0, 0);
#else
  f32x4 d;
  asm volatile("v_mfma_f32_16x16x16_bf16 %0, %1, %2, %3\n\ts_nop 7\n\ts_nop 7"
               : "=v"(d) : "v"(a), "v"(b), "v"(c));
  return d;
#endif
}

// ---------------------------------------------------------------------------
// fp32 -> bf16 conversion: y=0 hidden_states, y=1..4 weight matrices.
// ---------------------------------------------------------------------------
__global__ __launch_bounds__(256) void cvt_f32_bf16(
    const float* __restrict__ s0, bf16* __restrict__ d0, int n0,
    const float* __restrict__ s1, bf16* __restrict__ d1,
    const float* __restrict__ s2, bf16* __restrict__ d2,
    const float* __restrict__ s3, bf16* __restrict__ d3,
    const float* __restrict__ s4, bf16* __restrict__ d4, int nw)
{
  const float* s; bf16* d; int n;
  switch (blockIdx.y) {
    case 0:  s = s0; d = d0; n = n0; break;
    case 1:  s = s1; d = d1; n = nw; break;
    case 2:  s = s2; d = d2; n = nw; break;
    case 3:  s = s3; d = d3; n = nw; break;
    default: s = s4; d = d4; n = nw; break;
  }
  const int i = (blockIdx.x * 256 + threadIdx.x) * 8;
  if (i >= n) return;
  float4 v0 = *(const float4*)(s + i);
  float4 v1 = *(const float4*)(s + i + 4);
  bf16x8 o;
  o[0] = (bf16)v0.x; o[1] = (bf16)v0.y; o[2] = (bf16)v0.z; o[3] = (bf16)v0.w;
  o[4] = (bf16)v1.x; o[5] = (bf16)v1.y; o[6] = (bf16)v1.z; o[7] = (bf16)v1.w;
  *(bf16x8*)(d + i) = o;
}

// ---------------------------------------------------------------------------
// QKV GEMM (R10-proven): Y = (X·W^T + bias) * ysc, all-bf16 via glds16.
// 128x128 tile, BK=32, double-buffered LDS, one barrier per K-iter.
// ---------------------------------------------------------------------------
__global__ __launch_bounds__(256) void gemm_qkv(
    const bf16* __restrict__ X,
    const bf16* __restrict__ W0, const bf16* __restrict__ W1, const bf16* __restrict__ W2,
    const float* __restrict__ b0, const float* __restrict__ b1, const float* __restrict__ b2,
    bf16* __restrict__ Y0, bf16* __restrict__ Y1, bf16* __restrict__ Y2,
    float ys0, int M, int N, int K)
{
  const bf16* W; const float* bias; bf16* Y; float ysc;
  if (blockIdx.z == 0)      { W = W0; bias = b0; Y = Y0; ysc = ys0; }
  else if (blockIdx.z == 1) { W = W1; bias = b1; Y = Y1; ysc = 1.0f; }
  else                      { W = W2; bias = b2; Y = Y2; ysc = 1.0f; }

  __shared__ __align__(16) bf16 As[2][128 * 32];
  __shared__ __align__(16) bf16 Bs[2][128 * 32];

  const int tid  = threadIdx.x;
  const int lane = tid & 63;
  const int wave = tid >> 6;
  const int m0 = blockIdx.y * 128;
  const int n0 = blockIdx.x * 128;
  const int wm = (wave >> 1) * 64;
  const int wn = (wave & 1) * 64;

  const int r0 = tid >> 2,            c0 = (tid & 3) * 8;
  const int r1 = (256 + tid) >> 2,    c1 = ((256 + tid) & 3) * 8;
  const int cb0 = (wave * 64) * 8;
  const int cb1 = (256 + wave * 64) * 8;

  f32x4 acc[4][4] = {};

  glds16(X + (size_t)(m0 + r0) * K + c0, &As[0][cb0]);
  glds16(W + (size_t)(n0 + r0) * K + c0, &Bs[0][cb0]);
  glds16(X + (size_t)(m0 + r1) * K + c1, &As[0][cb1]);
  glds16(W + (size_t)(n0 + r1) * K + c1, &Bs[0][cb1]);

  int pb = 0;
  for (int k0 = 0; k0 < K; k0 += 32, pb ^= 1) {
    __syncthreads();

    if (k0 + 32 < K) {
      const int kn = k0 + 32;
      glds16(X + (size_t)(m0 + r0) * K + kn + c0, &As[pb ^ 1][cb0]);
      glds16(W + (size_t)(n0 + r0) * K + kn + c0, &Bs[pb ^ 1][cb0]);
      glds16(X + (size_t)(m0 + r1) * K + kn + c1, &As[pb ^ 1][cb1]);
      glds16(W + (size_t)(n0 + r1) * K + kn + c1, &Bs[pb ^ 1][cb1]);
    }

    bf16x8 a[4], b[4];
#pragma unroll
    for (int i = 0; i < 4; ++i)
      a[i] = *(const bf16x8*)&As[pb][(wm + i * 16 + (lane & 15)) * 32 + (lane >> 4) * 8];
#pragma unroll
    for (int i = 0; i < 4; ++i)
      b[i] = *(const bf16x8*)&Bs[pb][(wn + i * 16 + (lane & 15)) * 32 + (lane >> 4) * 8];
#pragma unroll
    for (int mi = 0; mi < 4; ++mi)
#pragma unroll
      for (int ni = 0; ni < 4; ++ni)
        acc[mi][ni] = __builtin_amdgcn_mfma_f32_16x16x32_bf16(a[mi], b[ni], acc[mi][ni], 0, 0, 0);
  }

#pragma unroll
  for (int mi = 0; mi < 4; ++mi) {
    const int row = m0 + wm + mi * 16 + (lane >> 4) * 4;
#pragma unroll
    for (int ni = 0; ni < 4; ++ni) {
      const int col = n0 + wn + ni * 16 + (lane & 15);
      const float bv = bias[col];
#pragma unroll
      for (int r = 0; r < 4; ++r)
        Y[(size_t)(row + r) * N + col] = (bf16)((acc[mi][ni][r] + bv) * ysc);
    }
  }
}

// ---------------------------------------------------------------------------
// O-projection (R10-proven): 64x128 tile, grid 8 x 64 = 512 blocks (2/CU).
// ---------------------------------------------------------------------------
__global__ __launch_bounds__(256) void gemm_o_64(
    const bf16* __restrict__ X, const bf16* __restrict__ W,
    const float* __restrict__ bias, float* __restrict__ Y)
{
  constexpr int K = 1024, N = 1024;
  __shared__ __align__(16) bf16 As[2][64 * 32];
  __shared__ __align__(16) bf16 Bs[2][128 * 32];

  const int tid  = threadIdx.x;
  const int lane = tid & 63;
  const int wave = tid >> 6;
  const int m0 = blockIdx.y * 64;
  const int n0 = blockIdx.x * 128;
  const int wm = (wave >> 1) * 32;
  const int wn = (wave & 1) * 64;

  const int ar = tid >> 2,  ac = (tid & 3) * 8;
  const int br0 = tid >> 2,          bc0 = (tid & 3) * 8;
  const int br1 = (256 + tid) >> 2,  bc1 = ((256 + tid) & 3) * 8;
  const int acb  = (wave * 64) * 8;
  const int bcb0 = (wave * 64) * 8;
  const int bcb1 = (256 + wave * 64) * 8;

  f32x4 acc[2][4] = {};

  glds16(X + (size_t)(m0 + ar) * K + ac,   &As[0][acb]);
  glds16(W + (size_t)(n0 + br0) * K + bc0, &Bs[0][bcb0]);
  glds16(W + (size_t)(n0 + br1) * K + bc1, &Bs[0][bcb1]);

  int pb = 0;
  for (int k0 = 0; k0 < K; k0 += 32, pb ^= 1) {
    __syncthreads();

    if (k0 + 32 < K) {
      const int kn = k0 + 32;
      glds16(X + (size_t)(m0 + ar) * K + kn + ac,   &As[pb ^ 1][acb]);
      glds16(W + (size_t)(n0 + br0) * K + kn + bc0, &Bs[pb ^ 1][bcb0]);
      glds16(W + (size_t)(n0 + br1) * K + kn + bc1, &Bs[pb ^ 1][bcb1]);
    }

    bf16x8 a[2], b[4];
#pragma unroll
    for (int i = 0; i < 2; ++i)
      a[i] = *(const bf16x8*)&As[pb][(wm + i * 16 + (lane & 15)) * 32 + (lane >> 4) * 8];
#pragma unroll
    for (int i = 0; i < 4; ++i)
      b[i] = *(const bf16x8*)&Bs[pb][(wn + i * 16 + (lane & 15)) * 32 + (lane >> 4) * 8];
#pragma unroll
    for (int mi = 0; mi < 2; ++mi)
#pragma unroll
      for (int ni = 0; ni < 4; ++ni)
        acc[mi][ni] = __builtin_amdgcn_mfma_f32_16x16x32_bf16(a[mi], b[ni], acc[mi][ni], 0, 0, 0);
  }

#pragma unroll
  for (int mi = 0; mi < 2; ++mi) {
    const int row = m0 + wm + mi * 16 + (lane >> 4) * 4;
#pragma unroll
    for (int ni = 0; ni < 4; ++ni) {
      const int col = n0 + wn + ni * 16 + (lane & 15);
      const float bv = bias[col];
#pragma unroll
      for (int r = 0; r < 4; ++r)
        Y[(size_t)(row + r) * N + col] = acc[mi][ni][r] + bv;
    }
  }
}

// ---------------------------------------------------------------------------
// Flash attention, causal.  R12: FUSED H+L tile-step with SHARED K/V LDS
// reads — each ak (b128) feeds sH and sL MFMAs; each av (b64) feeds oH and
// oL.  Cuts per-wave LDS read ops/iter from 24xb128+48xb64 (avg) to
// 16xb128+32xb64 (-35% LDS-pipe cycles — the measured per-CU invariant
// behind the 57.5us plateau).  Unlike R6 (spilled: array params through a
// function boundary), ALL softmax code is inlined via macros, all arrays
// indexed with compile-time constants, fixup AFTER PV (no pwv rescale).
// Peak live state ~190 VGPR; __launch_bounds__(256,2) gives 256/wave.
// Staging, swizzles, pairing, defer-max algebra: R10-verbatim.
// ---------------------------------------------------------------------------

// softmax for one half: mask (if last), max-tree (off-chain), speculative
// exp2 with current mr, row-sum; saves mx for the post-PV fixup.
#define SMAX(sacc, pwv, mr, lr, mxout, qrow_, last_)                        \
  {                                                                         \
    if (last_) {                                                            \
      _Pragma("unroll")                                                     \
      for (int mb = 0; mb < 8; ++mb) {                                      \
        const int kb = it * 128 + mb * 16 + quad * 4;                       \
        _Pragma("unroll")                                                   \
        for (int r = 0; r < 4; ++r)                                         \
          if (kb + r > (qrow_)) sacc[mb][r] = -1e30f;                       \
      }                                                                     \
    }                                                                       \
    float mx = -1e30f;                                                      \
    _Pragma("unroll")                                                       \
    for (int mb = 0; mb < 8; ++mb)                                          \
      mx = fmaxf(mx, fmaxf(fmaxf(sacc[mb][0], sacc[mb][1]),                 \
                           fmaxf(sacc[mb][2], sacc[mb][3])));               \
    mx = fmaxf(mx, __shfl_xor(mx, 16, 64));                                 \
    mx = fmaxf(mx, __shfl_xor(mx, 32, 64));                                 \
    (mxout) = mx;                                                           \
    float sum = 0.0f;                                                       \
    _Pragma("unroll")                                                       \
    for (int mb = 0; mb < 8; ++mb) {                                        \
      bf16x4 pw;                                                            \
      _Pragma("unroll")                                                     \
      for (int r = 0; r < 4; ++r) {                                         \
        const float p = __builtin_amdgcn_exp2f(sacc[mb][r] - (mr));         \
        sum += p;                                                           \
        pw[r] = (bf16)p;                                                    \
      }                                                                     \
      pwv[mb] = pw;                                                         \
    }                                                                       \
    sum += __shfl_xor(sum, 16, 64);                                         \
    sum += __shfl_xor(sum, 32, 64);                                         \
    (lr) += sum;                                                            \
  }

// rare fixup, AFTER PV accumulation (exact: O' = a*(O_old + P·V))
#define FIXUP(mx, mr, lr, oacc)                                             \
  if (!__all((mx) <= (mr) + 8.0f)) {                                        \
    const float mnew  = fmaxf((mr), (mx));                                  \
    const float alpha = __builtin_amdgcn_exp2f((mr) - mnew);                \
    (lr) *= alpha;                                                          \
    _Pragma("unroll")                                                       \
    for (int db = 0; db < 4; ++db)                                          \
      _Pragma("unroll")                                                     \
      for (int r = 0; r < 4; ++r) oacc[db][r] *= alpha;                     \
    (mr) = mnew;                                                            \
  }

__global__ __launch_bounds__(256, 2) void attn_causal(
    const bf16* __restrict__ Q, const bf16* __restrict__ K,
    const bf16* __restrict__ V, bf16* __restrict__ O)
{
  // XCD-chunked decode: all 16 pair-blocks of a bh land on one XCD (lin%8).
  const int lin  = blockIdx.x;               // 0..511
  const int slot = lin >> 3;                 // 0..63
  const int bh   = (lin & 7) * 4 + (slot >> 4);
  const int pair = slot & 15;
  const int b    = bh >> 4;
  const int h    = bh & 15;

  const int tid  = threadIdx.x;
  const int lane = tid & 63;
  const int wave = tid >> 6;
  const int quad = lane >> 4;
  const int l15  = lane & 15;
  const size_t headoff = (size_t)b * S_ * H_ + (size_t)h * HD_;
  const bf16* Kp = K + headoff;
  const bf16* Vp = V + headoff;

  __shared__ __align__(16) bf16 Ks[2][128 * 64];    // unpadded, XOR-swizzled
  __shared__ __align__(16) bf16 Vt[2][64 * 128];    // Vt[d][key], XOR-swizzled

  const int qlo = pair, qhi = 31 - pair;
  const int nl  = (qlo >> 1) + 1;      // 1..8
  const int nh  = (qhi >> 1) + 1;      // 9..16  (nl < nh always)
  const int qrowL = qlo * 64 + wave * 16 + l15;
  const int qrowH = qhi * 64 + wave * 16 + l15;

  // Q fragments in registers for the whole block (pre-scaled by QKV GEMM)
  bf16x8 bqL[2], bqH[2];
  bqL[0] = *(const bf16x8*)(Q + headoff + (size_t)qrowL * H_ + quad * 8);
  bqL[1] = *(const bf16x8*)(Q + headoff + (size_t)qrowL * H_ + 32 + quad * 8);
  bqH[0] = *(const bf16x8*)(Q + headoff + (size_t)qrowH * H_ + quad * 8);
  bqH[1] = *(const bf16x8*)(Q + headoff + (size_t)qrowH * H_ + 32 + quad * 8);

  const int vr = lane * 2;          // V: two adjacent key rows per thread
  const int vc = wave * 16;         //    16 of 64 head dims per wave

#define STAGE_K(k0_, buf_)                                                  \
  {                                                                         \
    _Pragma("unroll")                                                       \
    for (int j = 0; j < 4; ++j) {                                           \
      const int n = j * 256 + tid;                                          \
      const int row = n >> 3;                                               \
      const int cg  = (n & 7) ^ (row & 7);                                  \
      glds16(Kp + (size_t)((k0_) + row) * H_ + cg * 8,                      \
             &Ks[buf_][(j * 256 + wave * 64) * 8]);                         \
    }                                                                       \
  }

#define LOAD_V(k0_)                                                         \
  {                                                                         \
    vreg[0] = *(const bf16x8*)(Vp + (size_t)((k0_) + vr) * H_ + vc);        \
    vreg[1] = *(const bf16x8*)(Vp + (size_t)((k0_) + vr) * H_ + vc + 8);    \
    vreg[2] = *(const bf16x8*)(Vp + (size_t)((k0_) + vr + 1) * H_ + vc);    \
    vreg[3] = *(const bf16x8*)(Vp + (size_t)((k0_) + vr + 1) * H_ + vc + 8);\
  }

// Vt write with chunk-XOR swizzle: chunk (4 elems) index = (vr>>2) ^ (row&7).
#define WRITE_V(buf_)                                                       \
  {                                                                         \
    _Pragma("unroll")                                                       \
    for (int e = 0; e < 8; ++e) {                                           \
      const int sw = (((vr >> 2) ^ e) * 4) + (vr & 3);                      \
      bf16x2 p0; p0[0] = vreg[0][e]; p0[1] = vreg[2][e];                    \
      *(bf16x2*)&Vt[buf_][(vc + e) * 128 + sw] = p0;                        \
      bf16x2 p1; p1[0] = vreg[1][e]; p1[1] = vreg[3][e];                    \
      *(bf16x2*)&Vt[buf_][(vc + 8 + e) * 128 + sw] = p1;                    \
    }                                                                       \
  }

  bf16x8 vreg[4];

  // prologue: tile 0 -> buf 0
  STAGE_K(0, 0);
  LOAD_V(0);
  WRITE_V(0);
  __syncthreads();

  float mrL = 0.0f, lrL = 0.0f, mrH = 0.0f, lrH = 0.0f;
  f32x4 oL[4] = {}, oH[4] = {};

  for (int it = 0; it < nh; ++it) {
    const int c = it & 1;
    const bool pre = (it + 1 < nh);
    const bool doL = (it < nl);

    if (pre) {                       // prefetch tile it+1 into buf c^1
      STAGE_K((it + 1) * 128, c ^ 1);
      LOAD_V((it + 1) * 128);
    }

    // ---- fused S^T = K Q^T: each ak b128 read feeds BOTH q-tiles ----
    f32x4 sH[8] = {}, sL[8] = {};
    __builtin_amdgcn_s_setprio(1);
#pragma unroll
    for (int ks = 0; ks < 2; ++ks) {
#pragma unroll
      for (int mb = 0; mb < 8; ++mb) {
        const int row = mb * 16 + l15;
        const int ch  = (ks * 4 + quad) ^ (l15 & 7);   // XOR de-swizzle
        bf16x8 ak = *(const bf16x8*)&Ks[c][row * 64 + ch * 8];
        sH[mb] = __builtin_amdgcn_mfma_f32_16x16x32_bf16(ak, bqH[ks], sH[mb], 0, 0, 0);
        if (doL)
          sL[mb] = __builtin_amdgcn_mfma_f32_16x16x32_bf16(ak, bqL[ks], sL[mb], 0, 0, 0);
      }
    }
    __builtin_amdgcn_s_setprio(0);

    // ---- softmax, both halves (inline, no function boundary) ----
    bf16x4 pwH[8], pwL[8];
    float mxH = -1e30f, mxL = -1e30f;
    SMAX(sH, pwH, mrH, lrH, mxH, qrowH, it == nh - 1);
    if (doL)
      SMAX(sL, pwL, mrL, lrL, mxL, qrowL, it == nl - 1);

    // ---- fused O^T += V^T P^T: each av b64 read feeds BOTH q-tiles ----
    __builtin_amdgcn_s_setprio(1);
#pragma unroll
    for (int mb = 0; mb < 8; ++mb) {
#pragma unroll
      for (int db = 0; db < 4; ++db) {
        const int vch = ((mb * 4 + quad) ^ (l15 & 7)) * 4;
        bf16x4 av = *(const bf16x4*)&Vt[c][(db * 16 + l15) * 128 + vch];
        oH[db] = pv_mfma(av, pwH[mb], oH[db]);
        if (doL) oL[db] = pv_mfma(av, pwL[mb], oL[db]);
      }
    }
    __builtin_amdgcn_s_setprio(0);

    // ---- rare fixups (post-PV, exact algebra) ----
    FIXUP(mxH, mrH, lrH, oH);
    if (doL) FIXUP(mxL, mrL, lrL, oL);

    if (pre) {
      WRITE_V(c ^ 1);                // reg->LDS after compute (write-late)
      __syncthreads();               // drains glds + V writes; publishes c^1
    }
  }

  // epilogues
  const float invL = 1.0f / lrL;
#pragma unroll
  for (int db = 0; db < 4; ++db) {
    bf16x4 o;
#pragma unroll
    for (int r = 0; r < 4; ++r) o[r] = (bf16)(oL[db][r] * invL);
    *(bf16x4*)(O + headoff + (size_t)qrowL * H_ + db * 16 + quad * 4) = o;
  }
  const float invH = 1.0f / lrH;
#pragma unroll
  for (int db = 0; db < 4; ++db) {
    bf16x4 o;
#pragma unroll
    for (int r = 0; r < 4; ++r) o[r] = (bf16)(oH[db][r] * invH);
    *(bf16x4*)(O + headoff + (size_t)qrowH * H_ + db * 16 + quad * 4) = o;
  }
#undef STAGE_K
#undef LOAD_V
#undef WRITE_V
}

extern "C" void kernel_launch(void* const* d_in, const int* in_sizes, int n_in,
                              void* d_out, int out_size, void* d_ws, size_t ws_size,
                              hipStream_t stream) {
  const float* hs = (const float*)d_in[0];
  const float* Wq = (const float*)d_in[1]; const float* bq = (const float*)d_in[2];
  const float* Wk = (const float*)d_in[3]; const float* bk = (const float*)d_in[4];
  const float* Wv = (const float*)d_in[5]; const float* bv = (const float*)d_in[6];
  const float* Wo = (const float*)d_in[7]; const float* bo = (const float*)d_in[8];
  float* out = (float*)d_out;

  const size_t elems = (size_t)B_ * S_ * H_;   // 4,194,304
  const size_t wel   = (size_t)H_ * H_;        // 1,048,576
  // workspace (40 MB): [hsb | AO aliased 8MB][W bf16 8MB][Q 8][K 8][V 8]
  bf16* hsb = (bf16*)d_ws;      // read only by QKV GEMM
  bf16* AO  = hsb;              // written by attn (hsb dead by then)
  bf16* Wqb = hsb + elems;
  bf16* Wkb = Wqb + wel;
  bf16* Wvb = Wkb + wel;
  bf16* Wob = Wvb + wel;
  bf16* Qw  = Wob + wel;
  bf16* Kw  = Qw + elems;
  bf16* Vw  = Kw + elems;

  cvt_f32_bf16<<<dim3(2048, 5), dim3(256), 0, stream>>>(
      hs, hsb, (int)elems, Wq, Wqb, Wk, Wkb, Wv, Wvb, Wo, Wob, (int)wel);

  const int M = B_ * S_;   // 4096
  const float QSCL = 0.125f * 1.44269504f;   // (1/sqrt(64)) * log2(e)

  gemm_qkv<<<dim3(H_ / 128, M / 128, 3), dim3(256), 0, stream>>>(
      hsb, Wqb, Wkb, Wvb, bq, bk, bv, Qw, Kw, Vw, QSCL, M, H_, H_);

  attn_causal<<<dim3(512), dim3(256), 0, stream>>>(Qw, Kw, Vw, AO);

  gemm_o_64<<<dim3(8, 64), dim3(256), 0, stream>>>(AO, Wob, bo, out);
}

// Round 13
// 199.037 us; speedup vs baseline: 2.7034x; 2.7034x over previous
//
#include <hip/hip_runtime.h>
#include <stdint.h>

typedef __bf16 bf16;
typedef __attribute__((ext_vector_type(2))) __bf16 bf16x2;
typedef __attribute__((ext_vector_type(4))) __bf16 bf16x4;
typedef __attribute__((ext_vector_type(8))) __bf16 bf16x8;
typedef __attribute__((ext_vector_type(4))) float f32x4;
typedef __attribute__((ext_vector_type(4))) short s16x4;

#define B_  2
#define S_  2048
#define H_  1024
#define NH_ 16
#define HD_ 64

// async 16B global->LDS. LDS dest = wave-uniform base + lane*16.
__device__ __forceinline__ void glds16(const bf16* g, bf16* l) {
  __builtin_amdgcn_global_load_lds(
      (const __attribute__((address_space(1))) uint32_t*)g,
      (__attribute__((address_space(3))) uint32_t*)l, 16, 0, 0);
}

// PV MFMA: 16x16x16 bf16 — B operand layout (k=quad*4+e, col=l15) matches the
// S^T MFMA D layout exactly, so softmax P registers feed it with NO relayout.
__device__ __forceinline__ f32x4 pv_mfma(bf16x4 a, bf16x4 b, f32x4 c) {
#if __has_builtin(__builtin_amdgcn_mfma_f32_16x16x16bf16_1k)
  union U { bf16x4 h; s16x4 s; };
  U ua; ua.h = a;
  U ub; ub.h = b;
  return __builtin_amdgcn_mfma_f32_16x16x16bf16_1k(ua.s, ub.s, c, 0, 0, 0);
#else
  f32x4 d;
  asm volatile("v_mfma_f32_16x16x16_bf16 %0, %1, %2, %3\n\ts_nop 7\n\ts_nop 7"
               : "=v"(d) : "v"(a), "v"(b), "v"(c));
  return d;
#endif
}

// ---------------------------------------------------------------------------
// fp32 -> bf16 conversion: y=0 hidden_states, y=1..4 weight matrices.
// ---------------------------------------------------------------------------
__global__ __launch_bounds__(256) void cvt_f32_bf16(
    const float* __restrict__ s0, bf16* __restrict__ d0, int n0,
    const float* __restrict__ s1, bf16* __restrict__ d1,
    const float* __restrict__ s2, bf16* __restrict__ d2,
    const float* __restrict__ s3, bf16* __restrict__ d3,
    const float* __restrict__ s4, bf16* __restrict__ d4, int nw)
{
  const float* s; bf16* d; int n;
  switch (blockIdx.y) {
    case 0:  s = s0; d = d0; n = n0; break;
    case 1:  s = s1; d = d1; n = nw; break;
    case 2:  s = s2; d = d2; n = nw; break;
    case 3:  s = s3; d = d3; n = nw; break;
    default: s = s4; d = d4; n = nw; break;
  }
  const int i = (blockIdx.x * 256 + threadIdx.x) * 8;
  if (i >= n) return;
  float4 v0 = *(const float4*)(s + i);
  float4 v1 = *(const float4*)(s + i + 4);
  bf16x8 o;
  o[0] = (bf16)v0.x; o[1] = (bf16)v0.y; o[2] = (bf16)v0.z; o[3] = (bf16)v0.w;
  o[4] = (bf16)v1.x; o[5] = (bf16)v1.y; o[6] = (bf16)v1.z; o[7] = (bf16)v1.w;
  *(bf16x8*)(d + i) = o;
}

// ---------------------------------------------------------------------------
// QKV GEMM (R10-proven): Y = (X·W^T + bias) * ysc, all-bf16 via glds16.
// 128x128 tile, BK=32, double-buffered LDS, one barrier per K-iter.
// ---------------------------------------------------------------------------
__global__ __launch_bounds__(256) void gemm_qkv(
    const bf16* __restrict__ X,
    const bf16* __restrict__ W0, const bf16* __restrict__ W1, const bf16* __restrict__ W2,
    const float* __restrict__ b0, const float* __restrict__ b1, const float* __restrict__ b2,
    bf16* __restrict__ Y0, bf16* __restrict__ Y1, bf16* __restrict__ Y2,
    float ys0, int M, int N, int K)
{
  const bf16* W; const float* bias; bf16* Y; float ysc;
  if (blockIdx.z == 0)      { W = W0; bias = b0; Y = Y0; ysc = ys0; }
  else if (blockIdx.z == 1) { W = W1; bias = b1; Y = Y1; ysc = 1.0f; }
  else                      { W = W2; bias = b2; Y = Y2; ysc = 1.0f; }

  __shared__ __align__(16) bf16 As[2][128 * 32];
  __shared__ __align__(16) bf16 Bs[2][128 * 32];

  const int tid  = threadIdx.x;
  const int lane = tid & 63;
  const int wave = tid >> 6;
  const int m0 = blockIdx.y * 128;
  const int n0 = blockIdx.x * 128;
  const int wm = (wave >> 1) * 64;
  const int wn = (wave & 1) * 64;

  const int r0 = tid >> 2,            c0 = (tid & 3) * 8;
  const int r1 = (256 + tid) >> 2,    c1 = ((256 + tid) & 3) * 8;
  const int cb0 = (wave * 64) * 8;
  const int cb1 = (256 + wave * 64) * 8;

  f32x4 acc[4][4] = {};

  glds16(X + (size_t)(m0 + r0) * K + c0, &As[0][cb0]);
  glds16(W + (size_t)(n0 + r0) * K + c0, &Bs[0][cb0]);
  glds16(X + (size_t)(m0 + r1) * K + c1, &As[0][cb1]);
  glds16(W + (size_t)(n0 + r1) * K + c1, &Bs[0][cb1]);

  int pb = 0;
  for (int k0 = 0; k0 < K; k0 += 32, pb ^= 1) {
    __syncthreads();

    if (k0 + 32 < K) {
      const int kn = k0 + 32;
      glds16(X + (size_t)(m0 + r0) * K + kn + c0, &As[pb ^ 1][cb0]);
      glds16(W + (size_t)(n0 + r0) * K + kn + c0, &Bs[pb ^ 1][cb0]);
      glds16(X + (size_t)(m0 + r1) * K + kn + c1, &As[pb ^ 1][cb1]);
      glds16(W + (size_t)(n0 + r1) * K + kn + c1, &Bs[pb ^ 1][cb1]);
    }

    bf16x8 a[4], b[4];
#pragma unroll
    for (int i = 0; i < 4; ++i)
      a[i] = *(const bf16x8*)&As[pb][(wm + i * 16 + (lane & 15)) * 32 + (lane >> 4) * 8];
#pragma unroll
    for (int i = 0; i < 4; ++i)
      b[i] = *(const bf16x8*)&Bs[pb][(wn + i * 16 + (lane & 15)) * 32 + (lane >> 4) * 8];
#pragma unroll
    for (int mi = 0; mi < 4; ++mi)
#pragma unroll
      for (int ni = 0; ni < 4; ++ni)
        acc[mi][ni] = __builtin_amdgcn_mfma_f32_16x16x32_bf16(a[mi], b[ni], acc[mi][ni], 0, 0, 0);
  }

#pragma unroll
  for (int mi = 0; mi < 4; ++mi) {
    const int row = m0 + wm + mi * 16 + (lane >> 4) * 4;
#pragma unroll
    for (int ni = 0; ni < 4; ++ni) {
      const int col = n0 + wn + ni * 16 + (lane & 15);
      const float bv = bias[col];
#pragma unroll
      for (int r = 0; r < 4; ++r)
        Y[(size_t)(row + r) * N + col] = (bf16)((acc[mi][ni][r] + bv) * ysc);
    }
  }
}

// ---------------------------------------------------------------------------
// O-projection (R10-proven): 64x128 tile, grid 8 x 64 = 512 blocks (2/CU).
// ---------------------------------------------------------------------------
__global__ __launch_bounds__(256) void gemm_o_64(
    const bf16* __restrict__ X, const bf16* __restrict__ W,
    const float* __restrict__ bias, float* __restrict__ Y)
{
  constexpr int K = 1024, N = 1024;
  __shared__ __align__(16) bf16 As[2][64 * 32];
  __shared__ __align__(16) bf16 Bs[2][128 * 32];

  const int tid  = threadIdx.x;
  const int lane = tid & 63;
  const int wave = tid >> 6;
  const int m0 = blockIdx.y * 64;
  const int n0 = blockIdx.x * 128;
  const int wm = (wave >> 1) * 32;
  const int wn = (wave & 1) * 64;

  const int ar = tid >> 2,  ac = (tid & 3) * 8;
  const int br0 = tid >> 2,          bc0 = (tid & 3) * 8;
  const int br1 = (256 + tid) >> 2,  bc1 = ((256 + tid) & 3) * 8;
  const int acb  = (wave * 64) * 8;
  const int bcb0 = (wave * 64) * 8;
  const int bcb1 = (256 + wave * 64) * 8;

  f32x4 acc[2][4] = {};

  glds16(X + (size_t)(m0 + ar) * K + ac,   &As[0][acb]);
  glds16(W + (size_t)(n0 + br0) * K + bc0, &Bs[0][bcb0]);
  glds16(W + (size_t)(n0 + br1) * K + bc1, &Bs[0][bcb1]);

  int pb = 0;
  for (int k0 = 0; k0 < K; k0 += 32, pb ^= 1) {
    __syncthreads();

    if (k0 + 32 < K) {
      const int kn = k0 + 32;
      glds16(X + (size_t)(m0 + ar) * K + kn + ac,   &As[pb ^ 1][acb]);
      glds16(W + (size_t)(n0 + br0) * K + kn + bc0, &Bs[pb ^ 1][bcb0]);
      glds16(W + (size_t)(n0 + br1) * K + kn + bc1, &Bs[pb ^ 1][bcb1]);
    }

    bf16x8 a[2], b[4];
#pragma unroll
    for (int i = 0; i < 2; ++i)
      a[i] = *(const bf16x8*)&As[pb][(wm + i * 16 + (lane & 15)) * 32 + (lane >> 4) * 8];
#pragma unroll
    for (int i = 0; i < 4; ++i)
      b[i] = *(const bf16x8*)&Bs[pb][(wn + i * 16 + (lane & 15)) * 32 + (lane >> 4) * 8];
#pragma unroll
    for (int mi = 0; mi < 2; ++mi)
#pragma unroll
      for (int ni = 0; ni < 4; ++ni)
        acc[mi][ni] = __builtin_amdgcn_mfma_f32_16x16x32_bf16(a[mi], b[ni], acc[mi][ni], 0, 0, 0);
  }

#pragma unroll
  for (int mi = 0; mi < 2; ++mi) {
    const int row = m0 + wm + mi * 16 + (lane >> 4) * 4;
#pragma unroll
    for (int ni = 0; ni < 4; ++ni) {
      const int col = n0 + wn + ni * 16 + (lane & 15);
      const float bv = bias[col];
#pragma unroll
      for (int r = 0; r < 4; ++r)
        Y[(size_t)(row + r) * N + col] = acc[mi][ni][r] + bv;
    }
  }
}

// ===========================================================================
// Attention — two variants sharing the staging/softmax macros:
//   attn_fused : R12 fused H+L (shared K/V LDS reads, -35% LDS-pipe cycles)
//                with amdgpu_waves_per_eu(1) to unlock the >128 VGPR budget
//                that R6/R12 spilled against (both capped at exactly 128).
//   attn_safe  : R10 proven kernel (57.5 us, 88 VGPR).
// kernel_launch picks fused ONLY if hipFuncGetAttributes shows zero scratch
// (spill canary) and numRegs <= 256 (keeps 2 waves/SIMD).
// ===========================================================================

#define STAGE_K(k0_, buf_)                                                  \
  {                                                                         \
    _Pragma("unroll")                                                       \
    for (int j = 0; j < 4; ++j) {                                           \
      const int n = j * 256 + tid;                                          \
      const int row = n >> 3;                                               \
      const int cg  = (n & 7) ^ (row & 7);                                  \
      glds16(Kp + (size_t)((k0_) + row) * H_ + cg * 8,                      \
             &Ks[buf_][(j * 256 + wave * 64) * 8]);                         \
    }                                                                       \
  }

#define LOAD_V(k0_)                                                         \
  {                                                                         \
    vreg[0] = *(const bf16x8*)(Vp + (size_t)((k0_) + vr) * H_ + vc);        \
    vreg[1] = *(const bf16x8*)(Vp + (size_t)((k0_) + vr) * H_ + vc + 8);    \
    vreg[2] = *(const bf16x8*)(Vp + (size_t)((k0_) + vr + 1) * H_ + vc);    \
    vreg[3] = *(const bf16x8*)(Vp + (size_t)((k0_) + vr + 1) * H_ + vc + 8);\
  }

#define WRITE_V(buf_)                                                       \
  {                                                                         \
    _Pragma("unroll")                                                       \
    for (int e = 0; e < 8; ++e) {                                           \
      const int sw = (((vr >> 2) ^ e) * 4) + (vr & 3);                      \
      bf16x2 p0; p0[0] = vreg[0][e]; p0[1] = vreg[2][e];                    \
      *(bf16x2*)&Vt[buf_][(vc + e) * 128 + sw] = p0;                        \
      bf16x2 p1; p1[0] = vreg[1][e]; p1[1] = vreg[3][e];                    \
      *(bf16x2*)&Vt[buf_][(vc + 8 + e) * 128 + sw] = p1;                    \
    }                                                                       \
  }

// softmax for one half: mask (if last), max-tree (off-chain), speculative
// exp2 with current mr, row-sum; saves mx for the post-PV fixup.
#define SMAX(sacc, pwv, mr, lr, mxout, qrow_, last_)                        \
  {                                                                         \
    if (last_) {                                                            \
      _Pragma("unroll")                                                     \
      for (int mb = 0; mb < 8; ++mb) {                                      \
        const int kb = it * 128 + mb * 16 + quad * 4;                       \
        _Pragma("unroll")                                                   \
        for (int r = 0; r < 4; ++r)                                         \
          if (kb + r > (qrow_)) sacc[mb][r] = -1e30f;                       \
      }                                                                     \
    }                                                                       \
    float mx = -1e30f;                                                      \
    _Pragma("unroll")                                                       \
    for (int mb = 0; mb < 8; ++mb)                                          \
      mx = fmaxf(mx, fmaxf(fmaxf(sacc[mb][0], sacc[mb][1]),                 \
                           fmaxf(sacc[mb][2], sacc[mb][3])));               \
    mx = fmaxf(mx, __shfl_xor(mx, 16, 64));                                 \
    mx = fmaxf(mx, __shfl_xor(mx, 32, 64));                                 \
    (mxout) = mx;                                                           \
    float sum = 0.0f;                                                       \
    _Pragma("unroll")                                                       \
    for (int mb = 0; mb < 8; ++mb) {                                        \
      bf16x4 pw;                                                            \
      _Pragma("unroll")                                                     \
      for (int r = 0; r < 4; ++r) {                                         \
        const float p = __builtin_amdgcn_exp2f(sacc[mb][r] - (mr));         \
        sum += p;                                                           \
        pw[r] = (bf16)p;                                                    \
      }                                                                     \
      pwv[mb] = pw;                                                         \
    }                                                                       \
    sum += __shfl_xor(sum, 16, 64);                                         \
    sum += __shfl_xor(sum, 32, 64);                                         \
    (lr) += sum;                                                            \
  }

// rare fixup, AFTER PV accumulation (exact: O' = a*(O_old + P·V))
#define FIXUP(mx, mr, lr, oacc)                                             \
  if (!__all((mx) <= (mr) + 8.0f)) {                                        \
    const float mnew  = fmaxf((mr), (mx));                                  \
    const float alpha = __builtin_amdgcn_exp2f((mr) - mnew);                \
    (lr) *= alpha;                                                          \
    _Pragma("unroll")                                                       \
    for (int db = 0; db < 4; ++db)                                          \
      _Pragma("unroll")                                                     \
      for (int r = 0; r < 4; ++r) oacc[db][r] *= alpha;                     \
    (mr) = mnew;                                                            \
  }

// common per-block decode + Q-load, shared by both attn kernels
#define ATTN_PROLOGUE()                                                     \
  const int lin  = blockIdx.x;                                              \
  const int slot = lin >> 3;                                                \
  const int bh   = (lin & 7) * 4 + (slot >> 4);                             \
  const int pair = slot & 15;                                               \
  const int b    = bh >> 4;                                                 \
  const int h    = bh & 15;                                                 \
  const int tid  = threadIdx.x;                                             \
  const int lane = tid & 63;                                                \
  const int wave = tid >> 6;                                                \
  const int quad = lane >> 4;                                               \
  const int l15  = lane & 15;                                               \
  const size_t headoff = (size_t)b * S_ * H_ + (size_t)h * HD_;             \
  const bf16* Kp = K + headoff;                                             \
  const bf16* Vp = V + headoff;                                             \
  const int qlo = pair, qhi = 31 - pair;                                    \
  const int nl  = (qlo >> 1) + 1;                                           \
  const int nh  = (qhi >> 1) + 1;                                           \
  const int qrowL = qlo * 64 + wave * 16 + l15;                             \
  const int qrowH = qhi * 64 + wave * 16 + l15;                             \
  bf16x8 bqL[2], bqH[2];                                                    \
  bqL[0] = *(const bf16x8*)(Q + headoff + (size_t)qrowL * H_ + quad * 8);   \
  bqL[1] = *(const bf16x8*)(Q + headoff + (size_t)qrowL * H_ + 32 + quad * 8); \
  bqH[0] = *(const bf16x8*)(Q + headoff + (size_t)qrowH * H_ + quad * 8);   \
  bqH[1] = *(const bf16x8*)(Q + headoff + (size_t)qrowH * H_ + 32 + quad * 8); \
  const int vr = lane * 2;                                                  \
  const int vc = wave * 16;                                                 \
  bf16x8 vreg[4];

#define ATTN_EPILOGUE()                                                     \
  const float invL = 1.0f / lrL;                                            \
  _Pragma("unroll")                                                         \
  for (int db = 0; db < 4; ++db) {                                          \
    bf16x4 o;                                                               \
    _Pragma("unroll")                                                       \
    for (int r = 0; r < 4; ++r) o[r] = (bf16)(oL[db][r] * invL);            \
    *(bf16x4*)(O + headoff + (size_t)qrowL * H_ + db * 16 + quad * 4) = o;  \
  }                                                                         \
  const float invH = 1.0f / lrH;                                            \
  _Pragma("unroll")                                                         \
  for (int db = 0; db < 4; ++db) {                                          \
    bf16x4 o;                                                               \
    _Pragma("unroll")                                                       \
    for (int r = 0; r < 4; ++r) o[r] = (bf16)(oH[db][r] * invH);            \
    *(bf16x4*)(O + headoff + (size_t)qrowH * H_ + db * 16 + quad * 4) = o;  \
  }

// ---- fused variant: shared K/V reads, wide VGPR budget ----
__global__ __launch_bounds__(256)
__attribute__((amdgpu_waves_per_eu(1)))
void attn_fused(
    const bf16* __restrict__ Q, const bf16* __restrict__ K,
    const bf16* __restrict__ V, bf16* __restrict__ O)
{
  __shared__ __align__(16) bf16 Ks[2][128 * 64];
  __shared__ __align__(16) bf16 Vt[2][64 * 128];

  ATTN_PROLOGUE();

  STAGE_K(0, 0);
  LOAD_V(0);
  WRITE_V(0);
  __syncthreads();

  float mrL = 0.0f, lrL = 0.0f, mrH = 0.0f, lrH = 0.0f;
  f32x4 oL[4] = {}, oH[4] = {};

  for (int it = 0; it < nh; ++it) {
    const int c = it & 1;
    const bool pre = (it + 1 < nh);
    const bool doL = (it < nl);

    if (pre) {
      STAGE_K((it + 1) * 128, c ^ 1);
      LOAD_V((it + 1) * 128);
    }

    // fused S^T = K Q^T: each ak b128 read feeds BOTH q-tiles
    f32x4 sH[8] = {}, sL[8] = {};
    __builtin_amdgcn_s_setprio(1);
#pragma unroll
    for (int ks = 0; ks < 2; ++ks) {
#pragma unroll
      for (int mb = 0; mb < 8; ++mb) {
        const int row = mb * 16 + l15;
        const int ch  = (ks * 4 + quad) ^ (l15 & 7);
        bf16x8 ak = *(const bf16x8*)&Ks[c][row * 64 + ch * 8];
        sH[mb] = __builtin_amdgcn_mfma_f32_16x16x32_bf16(ak, bqH[ks], sH[mb], 0, 0, 0);
        if (doL)
          sL[mb] = __builtin_amdgcn_mfma_f32_16x16x32_bf16(ak, bqL[ks], sL[mb], 0, 0, 0);
      }
    }
    __builtin_amdgcn_s_setprio(0);

    bf16x4 pwH[8], pwL[8];
    float mxH = -1e30f, mxL = -1e30f;
    SMAX(sH, pwH, mrH, lrH, mxH, qrowH, it == nh - 1);
    if (doL)
      SMAX(sL, pwL, mrL, lrL, mxL, qrowL, it == nl - 1);

    // fused O^T += V^T P^T: each av b64 read feeds BOTH q-tiles
    __builtin_amdgcn_s_setprio(1);
#pragma unroll
    for (int mb = 0; mb < 8; ++mb) {
#pragma unroll
      for (int db = 0; db < 4; ++db) {
        const int vch = ((mb * 4 + quad) ^ (l15 & 7)) * 4;
        bf16x4 av = *(const bf16x4*)&Vt[c][(db * 16 + l15) * 128 + vch];
        oH[db] = pv_mfma(av, pwH[mb], oH[db]);
        if (doL) oL[db] = pv_mfma(av, pwL[mb], oL[db]);
      }
    }
    __builtin_amdgcn_s_setprio(0);

    FIXUP(mxH, mrH, lrH, oH);
    if (doL) FIXUP(mxL, mrL, lrL, oL);

    if (pre) {
      WRITE_V(c ^ 1);
      __syncthreads();
    }
  }

  ATTN_EPILOGUE();
}

// ---- safe variant: R10 proven (57.5 us, 88 VGPR) ----
__device__ __forceinline__ void attn_tile_step(
    const bf16* Ksb, const bf16* Vtb, const bf16x8 bq[2], int qrow, int k0,
    bool maskit, float& mr, float& lr, f32x4 oacc[4], int l15, int quad)
{
  f32x4 sacc[8] = {};
  __builtin_amdgcn_s_setprio(1);
#pragma unroll
  for (int ks = 0; ks < 2; ++ks) {
#pragma unroll
    for (int mb = 0; mb < 8; ++mb) {
      const int row = mb * 16 + l15;
      const int ch  = (ks * 4 + quad) ^ (l15 & 7);
      bf16x8 ak = *(const bf16x8*)&Ksb[row * 64 + ch * 8];
      sacc[mb] = __builtin_amdgcn_mfma_f32_16x16x32_bf16(ak, bq[ks], sacc[mb], 0, 0, 0);
    }
  }
  __builtin_amdgcn_s_setprio(0);

  if (maskit) {
#pragma unroll
    for (int mb = 0; mb < 8; ++mb) {
      const int kb = k0 + mb * 16 + quad * 4;
#pragma unroll
      for (int r = 0; r < 4; ++r)
        if (kb + r > qrow) sacc[mb][r] = -1e30f;
    }
  }

  float mx = -1e30f;
#pragma unroll
  for (int mb = 0; mb < 8; ++mb)
    mx = fmaxf(mx, fmaxf(fmaxf(sacc[mb][0], sacc[mb][1]),
                         fmaxf(sacc[mb][2], sacc[mb][3])));
  mx = fmaxf(mx, __shfl_xor(mx, 16, 64));
  mx = fmaxf(mx, __shfl_xor(mx, 32, 64));

  float sum = 0.0f;
  bf16x4 pwv[8];
#pragma unroll
  for (int mb = 0; mb < 8; ++mb) {
    bf16x4 pw;
#pragma unroll
    for (int r = 0; r < 4; ++r) {
      const float p = __builtin_amdgcn_exp2f(sacc[mb][r] - mr);
      sum += p;
      pw[r] = (bf16)p;
    }
    pwv[mb] = pw;
  }
  sum += __shfl_xor(sum, 16, 64);
  sum += __shfl_xor(sum, 32, 64);

  __builtin_amdgcn_s_setprio(1);
#pragma unroll
  for (int mb = 0; mb < 8; ++mb) {
#pragma unroll
    for (int db = 0; db < 4; ++db) {
      const int vch = ((mb * 4 + quad) ^ (l15 & 7)) * 4;
      bf16x4 av = *(const bf16x4*)&Vtb[(db * 16 + l15) * 128 + vch];
      oacc[db] = pv_mfma(av, pwv[mb], oacc[db]);
    }
  }
  __builtin_amdgcn_s_setprio(0);

  lr += sum;
  if (!__all(mx <= mr + 8.0f)) {
    const float mnew  = fmaxf(mr, mx);
    const float alpha = __builtin_amdgcn_exp2f(mr - mnew);
    lr *= alpha;
#pragma unroll
    for (int db = 0; db < 4; ++db)
#pragma unroll
      for (int r = 0; r < 4; ++r) oacc[db][r] *= alpha;
    mr = mnew;
  }
}

__global__ __launch_bounds__(256, 2) void attn_safe(
    const bf16* __restrict__ Q, const bf16* __restrict__ K,
    const bf16* __restrict__ V, bf16* __restrict__ O)
{
  __shared__ __align__(16) bf16 Ks[2][128 * 64];
  __shared__ __align__(16) bf16 Vt[2][64 * 128];

  ATTN_PROLOGUE();

  STAGE_K(0, 0);
  LOAD_V(0);
  WRITE_V(0);
  __syncthreads();

  float mrL = 0.0f, lrL = 0.0f, mrH = 0.0f, lrH = 0.0f;
  f32x4 oL[4] = {}, oH[4] = {};

  for (int it = 0; it < nh; ++it) {
    const int c = it & 1;
    const bool pre = (it + 1 < nh);

    if (pre) {
      STAGE_K((it + 1) * 128, c ^ 1);
      LOAD_V((it + 1) * 128);
    }

    attn_tile_step(Ks[c], Vt[c], bqH, qrowH, it * 128, it == nh - 1,
                   mrH, lrH, oH, l15, quad);
    if (it < nl)
      attn_tile_step(Ks[c], Vt[c], bqL, qrowL, it * 128, it == nl - 1,
                     mrL, lrL, oL, l15, quad);

    if (pre) {
      WRITE_V(c ^ 1);
      __syncthreads();
    }
  }

  ATTN_EPILOGUE();
}

extern "C" void kernel_launch(void* const* d_in, const int* in_sizes, int n_in,
                              void* d_out, int out_size, void* d_ws, size_t ws_size,
                              hipStream_t stream) {
  const float* hs = (const float*)d_in[0];
  const float* Wq = (const float*)d_in[1]; const float* bq = (const float*)d_in[2];
  const float* Wk = (const float*)d_in[3]; const float* bk = (const float*)d_in[4];
  const float* Wv = (const float*)d_in[5]; const float* bv = (const float*)d_in[6];
  const float* Wo = (const float*)d_in[7]; const float* bo = (const float*)d_in[8];
  float* out = (float*)d_out;

  const size_t elems = (size_t)B_ * S_ * H_;   // 4,194,304
  const size_t wel   = (size_t)H_ * H_;        // 1,048,576
  // workspace (40 MB): [hsb | AO aliased 8MB][W bf16 8MB][Q 8][K 8][V 8]
  bf16* hsb = (bf16*)d_ws;      // read only by QKV GEMM
  bf16* AO  = hsb;              // written by attn (hsb dead by then)
  bf16* Wqb = hsb + elems;
  bf16* Wkb = Wqb + wel;
  bf16* Wvb = Wkb + wel;
  bf16* Wob = Wvb + wel;
  bf16* Qw  = Wob + wel;
  bf16* Kw  = Qw + elems;
  bf16* Vw  = Kw + elems;

  // one-time spill-canary check: use the fused attn only if it compiled
  // without scratch (localSizeBytes==0) and keeps 2 waves/SIMD (<=256 regs).
  static int use_fused = -1;
  if (use_fused < 0) {
    hipFuncAttributes fa;
    if (hipFuncGetAttributes(&fa, (const void*)attn_fused) == hipSuccess &&
        fa.localSizeBytes == 0 && fa.numRegs <= 256)
      use_fused = 1;
    else
      use_fused = 0;
  }

  cvt_f32_bf16<<<dim3(2048, 5), dim3(256), 0, stream>>>(
      hs, hsb, (int)elems, Wq, Wqb, Wk, Wkb, Wv, Wvb, Wo, Wob, (int)wel);

  const int M = B_ * S_;   // 4096
  const float QSCL = 0.125f * 1.44269504f;   // (1/sqrt(64)) * log2(e)

  gemm_qkv<<<dim3(H_ / 128, M / 128, 3), dim3(256), 0, stream>>>(
      hsb, Wqb, Wkb, Wvb, bq, bk, bv, Qw, Kw, Vw, QSCL, M, H_, H_);

  if (use_fused)
    attn_fused<<<dim3(512), dim3(256), 0, stream>>>(Qw, Kw, Vw, AO);
  else
    attn_safe<<<dim3(512), dim3(256), 0, stream>>>(Qw, Kw, Vw, AO);

  gemm_o_64<<<dim3(8, 64), dim3(256), 0, stream>>>(AO, Wob, bo, out);
}

// Round 14
// 196.910 us; speedup vs baseline: 2.7326x; 1.0108x over previous
//
#include <hip/hip_runtime.h>
#include <stdint.h>

typedef __bf16 bf16;
typedef __attribute__((ext_vector_type(2))) __bf16 bf16x2;
typedef __attribute__((ext_vector_type(4))) __bf16 bf16x4;
typedef __attribute__((ext_vector_type(8))) __bf16 bf16x8;
typedef __attribute__((ext_vector_type(4))) float f32x4;
typedef __attribute__((ext_vector_type(4))) short s16x4;

#define B_  2
#define S_  2048
#define H_  1024
#define NH_ 16
#define HD_ 64

// async 16B global->LDS. LDS dest = wave-uniform base + lane*16.
__device__ __forceinline__ void glds16(const bf16* g, bf16* l) {
  __builtin_amdgcn_global_load_lds(
      (const __attribute__((address_space(1))) uint32_t*)g,
      (__attribute__((address_space(3))) uint32_t*)l, 16, 0, 0);
}

// PV MFMA: 16x16x16 bf16 — B operand layout (k=quad*4+e, col=l15) matches the
// S^T MFMA D layout exactly, so softmax P registers feed it with NO relayout.
__device__ __forceinline__ f32x4 pv_mfma(bf16x4 a, bf16x4 b, f32x4 c) {
#if __has_builtin(__builtin_amdgcn_mfma_f32_16x16x16bf16_1k)
  union U { bf16x4 h; s16x4 s; };
  U ua; ua.h = a;
  U ub; ub.h = b;
  return __builtin_amdgcn_mfma_f32_16x16x16bf16_1k(ua.s, ub.s, c, 0, 0, 0);
#else
  f32x4 d;
  asm volatile("v_mfma_f32_16x16x16_bf16 %0, %1, %2, %3\n\ts_nop 7\n\ts_nop 7"
               : "=v"(d) : "v"(a), "v"(b), "v"(c));
  return d;
#endif
}

// ---------------------------------------------------------------------------
// fp32 -> bf16 conversion: y=0 hidden_states, y=1..4 weight matrices.
// ---------------------------------------------------------------------------
__global__ __launch_bounds__(256) void cvt_f32_bf16(
    const float* __restrict__ s0, bf16* __restrict__ d0, int n0,
    const float* __restrict__ s1, bf16* __restrict__ d1,
    const float* __restrict__ s2, bf16* __restrict__ d2,
    const float* __restrict__ s3, bf16* __restrict__ d3,
    const float* __restrict__ s4, bf16* __restrict__ d4, int nw)
{
  const float* s; bf16* d; int n;
  switch (blockIdx.y) {
    case 0:  s = s0; d = d0; n = n0; break;
    case 1:  s = s1; d = d1; n = nw; break;
    case 2:  s = s2; d = d2; n = nw; break;
    case 3:  s = s3; d = d3; n = nw; break;
    default: s = s4; d = d4; n = nw; break;
  }
  const int i = (blockIdx.x * 256 + threadIdx.x) * 8;
  if (i >= n) return;
  float4 v0 = *(const float4*)(s + i);
  float4 v1 = *(const float4*)(s + i + 4);
  bf16x8 o;
  o[0] = (bf16)v0.x; o[1] = (bf16)v0.y; o[2] = (bf16)v0.z; o[3] = (bf16)v0.w;
  o[4] = (bf16)v1.x; o[5] = (bf16)v1.y; o[6] = (bf16)v1.z; o[7] = (bf16)v1.w;
  *(bf16x8*)(d + i) = o;
}

// ---------------------------------------------------------------------------
// QKV GEMM (R10-proven): Y = (X·W^T + bias) * ysc, all-bf16 via glds16.
// 128x128 tile, BK=32, double-buffered LDS, one barrier per K-iter.
// ---------------------------------------------------------------------------
__global__ __launch_bounds__(256) void gemm_qkv(
    const bf16* __restrict__ X,
    const bf16* __restrict__ W0, const bf16* __restrict__ W1, const bf16* __restrict__ W2,
    const float* __restrict__ b0, const float* __restrict__ b1, const float* __restrict__ b2,
    bf16* __restrict__ Y0, bf16* __restrict__ Y1, bf16* __restrict__ Y2,
    float ys0, int M, int N, int K)
{
  const bf16* W; const float* bias; bf16* Y; float ysc;
  if (blockIdx.z == 0)      { W = W0; bias = b0; Y = Y0; ysc = ys0; }
  else if (blockIdx.z == 1) { W = W1; bias = b1; Y = Y1; ysc = 1.0f; }
  else                      { W = W2; bias = b2; Y = Y2; ysc = 1.0f; }

  __shared__ __align__(16) bf16 As[2][128 * 32];
  __shared__ __align__(16) bf16 Bs[2][128 * 32];

  const int tid  = threadIdx.x;
  const int lane = tid & 63;
  const int wave = tid >> 6;
  const int m0 = blockIdx.y * 128;
  const int n0 = blockIdx.x * 128;
  const int wm = (wave >> 1) * 64;
  const int wn = (wave & 1) * 64;

  const int r0 = tid >> 2,            c0 = (tid & 3) * 8;
  const int r1 = (256 + tid) >> 2,    c1 = ((256 + tid) & 3) * 8;
  const int cb0 = (wave * 64) * 8;
  const int cb1 = (256 + wave * 64) * 8;

  f32x4 acc[4][4] = {};

  glds16(X + (size_t)(m0 + r0) * K + c0, &As[0][cb0]);
  glds16(W + (size_t)(n0 + r0) * K + c0, &Bs[0][cb0]);
  glds16(X + (size_t)(m0 + r1) * K + c1, &As[0][cb1]);
  glds16(W + (size_t)(n0 + r1) * K + c1, &Bs[0][cb1]);

  int pb = 0;
  for (int k0 = 0; k0 < K; k0 += 32, pb ^= 1) {
    __syncthreads();

    if (k0 + 32 < K) {
      const int kn = k0 + 32;
      glds16(X + (size_t)(m0 + r0) * K + kn + c0, &As[pb ^ 1][cb0]);
      glds16(W + (size_t)(n0 + r0) * K + kn + c0, &Bs[pb ^ 1][cb0]);
      glds16(X + (size_t)(m0 + r1) * K + kn + c1, &As[pb ^ 1][cb1]);
      glds16(W + (size_t)(n0 + r1) * K + kn + c1, &Bs[pb ^ 1][cb1]);
    }

    bf16x8 a[4], b[4];
#pragma unroll
    for (int i = 0; i < 4; ++i)
      a[i] = *(const bf16x8*)&As[pb][(wm + i * 16 + (lane & 15)) * 32 + (lane >> 4) * 8];
#pragma unroll
    for (int i = 0; i < 4; ++i)
      b[i] = *(const bf16x8*)&Bs[pb][(wn + i * 16 + (lane & 15)) * 32 + (lane >> 4) * 8];
#pragma unroll
    for (int mi = 0; mi < 4; ++mi)
#pragma unroll
      for (int ni = 0; ni < 4; ++ni)
        acc[mi][ni] = __builtin_amdgcn_mfma_f32_16x16x32_bf16(a[mi], b[ni], acc[mi][ni], 0, 0, 0);
  }

#pragma unroll
  for (int mi = 0; mi < 4; ++mi) {
    const int row = m0 + wm + mi * 16 + (lane >> 4) * 4;
#pragma unroll
    for (int ni = 0; ni < 4; ++ni) {
      const int col = n0 + wn + ni * 16 + (lane & 15);
      const float bv = bias[col];
#pragma unroll
      for (int r = 0; r < 4; ++r)
        Y[(size_t)(row + r) * N + col] = (bf16)((acc[mi][ni][r] + bv) * ysc);
    }
  }
}

// ---------------------------------------------------------------------------
// O-projection (R10-proven): 64x128 tile, grid 8 x 64 = 512 blocks (2/CU).
// ---------------------------------------------------------------------------
__global__ __launch_bounds__(256) void gemm_o_64(
    const bf16* __restrict__ X, const bf16* __restrict__ W,
    const float* __restrict__ bias, float* __restrict__ Y)
{
  constexpr int K = 1024, N = 1024;
  __shared__ __align__(16) bf16 As[2][64 * 32];
  __shared__ __align__(16) bf16 Bs[2][128 * 32];

  const int tid  = threadIdx.x;
  const int lane = tid & 63;
  const int wave = tid >> 6;
  const int m0 = blockIdx.y * 64;
  const int n0 = blockIdx.x * 128;
  const int wm = (wave >> 1) * 32;
  const int wn = (wave & 1) * 64;

  const int ar = tid >> 2,  ac = (tid & 3) * 8;
  const int br0 = tid >> 2,          bc0 = (tid & 3) * 8;
  const int br1 = (256 + tid) >> 2,  bc1 = ((256 + tid) & 3) * 8;
  const int acb  = (wave * 64) * 8;
  const int bcb0 = (wave * 64) * 8;
  const int bcb1 = (256 + wave * 64) * 8;

  f32x4 acc[2][4] = {};

  glds16(X + (size_t)(m0 + ar) * K + ac,   &As[0][acb]);
  glds16(W + (size_t)(n0 + br0) * K + bc0, &Bs[0][bcb0]);
  glds16(W + (size_t)(n0 + br1) * K + bc1, &Bs[0][bcb1]);

  int pb = 0;
  for (int k0 = 0; k0 < K; k0 += 32, pb ^= 1) {
    __syncthreads();

    if (k0 + 32 < K) {
      const int kn = k0 + 32;
      glds16(X + (size_t)(m0 + ar) * K + kn + ac,   &As[pb ^ 1][acb]);
      glds16(W + (size_t)(n0 + br0) * K + kn + bc0, &Bs[pb ^ 1][bcb0]);
      glds16(W + (size_t)(n0 + br1) * K + kn + bc1, &Bs[pb ^ 1][bcb1]);
    }

    bf16x8 a[2], b[4];
#pragma unroll
    for (int i = 0; i < 2; ++i)
      a[i] = *(const bf16x8*)&As[pb][(wm + i * 16 + (lane & 15)) * 32 + (lane >> 4) * 8];
#pragma unroll
    for (int i = 0; i < 4; ++i)
      b[i] = *(const bf16x8*)&Bs[pb][(wn + i * 16 + (lane & 15)) * 32 + (lane >> 4) * 8];
#pragma unroll
    for (int mi = 0; mi < 2; ++mi)
#pragma unroll
      for (int ni = 0; ni < 4; ++ni)
        acc[mi][ni] = __builtin_amdgcn_mfma_f32_16x16x32_bf16(a[mi], b[ni], acc[mi][ni], 0, 0, 0);
  }

#pragma unroll
  for (int mi = 0; mi < 2; ++mi) {
    const int row = m0 + wm + mi * 16 + (lane >> 4) * 4;
#pragma unroll
    for (int ni = 0; ni < 4; ++ni) {
      const int col = n0 + wn + ni * 16 + (lane & 15);
      const float bv = bias[col];
#pragma unroll
      for (int r = 0; r < 4; ++r)
        Y[(size_t)(row + r) * N + col] = acc[mi][ni][r] + bv;
    }
  }
}

// ===========================================================================
// Attention — two variants:
//   attn_fused : R14 split-loop fusion.  Loop 1 (it < nl): BOTH q-tiles,
//                fully straight-line (no conditional MFMA — the R6/R12
//                spill signature: both capped at 128 VGPR with `if(doL)`
//                selects inside 4-deep unrolled MFMA loops).  Loop 2
//                (nl..nh): H-only via the proven tile-step.  Shared K/V
//                LDS reads in loop 1 cut LDS read ops ~27% net.
//   attn_safe  : R10 proven kernel (57.1 us, 88 VGPR).
// kernel_launch picks fused ONLY if hipFuncGetAttributes shows zero scratch
// (spill canary) and numRegs <= 256 (keeps 2 waves/SIMD).
// ===========================================================================

#define STAGE_K(k0_, buf_)                                                  \
  {                                                                         \
    _Pragma("unroll")                                                       \
    for (int j = 0; j < 4; ++j) {                                           \
      const int n = j * 256 + tid;                                          \
      const int row = n >> 3;                                               \
      const int cg  = (n & 7) ^ (row & 7);                                  \
      glds16(Kp + (size_t)((k0_) + row) * H_ + cg * 8,                      \
             &Ks[buf_][(j * 256 + wave * 64) * 8]);                         \
    }                                                                       \
  }

#define LOAD_V(k0_)                                                         \
  {                                                                         \
    vreg[0] = *(const bf16x8*)(Vp + (size_t)((k0_) + vr) * H_ + vc);        \
    vreg[1] = *(const bf16x8*)(Vp + (size_t)((k0_) + vr) * H_ + vc + 8);    \
    vreg[2] = *(const bf16x8*)(Vp + (size_t)((k0_) + vr + 1) * H_ + vc);    \
    vreg[3] = *(const bf16x8*)(Vp + (size_t)((k0_) + vr + 1) * H_ + vc + 8);\
  }

#define WRITE_V(buf_)                                                       \
  {                                                                         \
    _Pragma("unroll")                                                       \
    for (int e = 0; e < 8; ++e) {                                           \
      const int sw = (((vr >> 2) ^ e) * 4) + (vr & 3);                      \
      bf16x2 p0; p0[0] = vreg[0][e]; p0[1] = vreg[2][e];                    \
      *(bf16x2*)&Vt[buf_][(vc + e) * 128 + sw] = p0;                        \
      bf16x2 p1; p1[0] = vreg[1][e]; p1[1] = vreg[3][e];                    \
      *(bf16x2*)&Vt[buf_][(vc + 8 + e) * 128 + sw] = p1;                    \
    }                                                                       \
  }

// softmax for one half: mask (if last), max-tree (off-chain), speculative
// exp2 with current mr, row-sum; saves mx for the post-PV fixup.
#define SMAX(sacc, pwv, mr, lr, mxout, qrow_, last_)                        \
  {                                                                         \
    if (last_) {                                                            \
      _Pragma("unroll")                                                     \
      for (int mb = 0; mb < 8; ++mb) {                                      \
        const int kb = it * 128 + mb * 16 + quad * 4;                       \
        _Pragma("unroll")                                                   \
        for (int r = 0; r < 4; ++r)                                         \
          if (kb + r > (qrow_)) sacc[mb][r] = -1e30f;                       \
      }                                                                     \
    }                                                                       \
    float mx = -1e30f;                                                      \
    _Pragma("unroll")                                                       \
    for (int mb = 0; mb < 8; ++mb)                                          \
      mx = fmaxf(mx, fmaxf(fmaxf(sacc[mb][0], sacc[mb][1]),                 \
                           fmaxf(sacc[mb][2], sacc[mb][3])));               \
    mx = fmaxf(mx, __shfl_xor(mx, 16, 64));                                 \
    mx = fmaxf(mx, __shfl_xor(mx, 32, 64));                                 \
    (mxout) = mx;                                                           \
    float sum = 0.0f;                                                       \
    _Pragma("unroll")                                                       \
    for (int mb = 0; mb < 8; ++mb) {                                        \
      bf16x4 pw;                                                            \
      _Pragma("unroll")                                                     \
      for (int r = 0; r < 4; ++r) {                                         \
        const float p = __builtin_amdgcn_exp2f(sacc[mb][r] - (mr));         \
        sum += p;                                                           \
        pw[r] = (bf16)p;                                                    \
      }                                                                     \
      pwv[mb] = pw;                                                         \
    }                                                                       \
    sum += __shfl_xor(sum, 16, 64);                                         \
    sum += __shfl_xor(sum, 32, 64);                                         \
    (lr) += sum;                                                            \
  }

// rare fixup, AFTER PV accumulation (exact: O' = a*(O_old + P·V))
#define FIXUP(mx, mr, lr, oacc)                                             \
  if (!__all((mx) <= (mr) + 8.0f)) {                                        \
    const float mnew  = fmaxf((mr), (mx));                                  \
    const float alpha = __builtin_amdgcn_exp2f((mr) - mnew);                \
    (lr) *= alpha;                                                          \
    _Pragma("unroll")                                                       \
    for (int db = 0; db < 4; ++db)                                          \
      _Pragma("unroll")                                                     \
      for (int r = 0; r < 4; ++r) oacc[db][r] *= alpha;                     \
    (mr) = mnew;                                                            \
  }

// common per-block decode + Q-load, shared by both attn kernels
#define ATTN_PROLOGUE()                                                     \
  const int lin  = blockIdx.x;                                              \
  const int slot = lin >> 3;                                                \
  const int bh   = (lin & 7) * 4 + (slot >> 4);                             \
  const int pair = slot & 15;                                               \
  const int b    = bh >> 4;                                                 \
  const int h    = bh & 15;                                                 \
  const int tid  = threadIdx.x;                                             \
  const int lane = tid & 63;                                                \
  const int wave = tid >> 6;                                                \
  const int quad = lane >> 4;                                               \
  const int l15  = lane & 15;                                               \
  const size_t headoff = (size_t)b * S_ * H_ + (size_t)h * HD_;             \
  const bf16* Kp = K + headoff;                                             \
  const bf16* Vp = V + headoff;                                             \
  const int qlo = pair, qhi = 31 - pair;                                    \
  const int nl  = (qlo >> 1) + 1;                                           \
  const int nh  = (qhi >> 1) + 1;                                           \
  const int qrowL = qlo * 64 + wave * 16 + l15;                             \
  const int qrowH = qhi * 64 + wave * 16 + l15;                             \
  bf16x8 bqL[2], bqH[2];                                                    \
  bqL[0] = *(const bf16x8*)(Q + headoff + (size_t)qrowL * H_ + quad * 8);   \
  bqL[1] = *(const bf16x8*)(Q + headoff + (size_t)qrowL * H_ + 32 + quad * 8); \
  bqH[0] = *(const bf16x8*)(Q + headoff + (size_t)qrowH * H_ + quad * 8);   \
  bqH[1] = *(const bf16x8*)(Q + headoff + (size_t)qrowH * H_ + 32 + quad * 8); \
  const int vr = lane * 2;                                                  \
  const int vc = wave * 16;                                                 \
  bf16x8 vreg[4];

#define ATTN_EPILOGUE()                                                     \
  const float invL = 1.0f / lrL;                                            \
  _Pragma("unroll")                                                         \
  for (int db = 0; db < 4; ++db) {                                          \
    bf16x4 o;                                                               \
    _Pragma("unroll")                                                       \
    for (int r = 0; r < 4; ++r) o[r] = (bf16)(oL[db][r] * invL);            \
    *(bf16x4*)(O + headoff + (size_t)qrowL * H_ + db * 16 + quad * 4) = o;  \
  }                                                                         \
  const float invH = 1.0f / lrH;                                            \
  _Pragma("unroll")                                                         \
  for (int db = 0; db < 4; ++db) {                                          \
    bf16x4 o;                                                               \
    _Pragma("unroll")                                                       \
    for (int r = 0; r < 4; ++r) o[r] = (bf16)(oH[db][r] * invH);            \
    *(bf16x4*)(O + headoff + (size_t)qrowH * H_ + db * 16 + quad * 4) = o;  \
  }

// ---- shared single-tile step (used by attn_safe and fused loop 2) ----
__device__ __forceinline__ void attn_tile_step(
    const bf16* Ksb, const bf16* Vtb, const bf16x8 bq[2], int qrow, int k0,
    bool maskit, float& mr, float& lr, f32x4 oacc[4], int l15, int quad)
{
  f32x4 sacc[8] = {};
  __builtin_amdgcn_s_setprio(1);
#pragma unroll
  for (int ks = 0; ks < 2; ++ks) {
#pragma unroll
    for (int mb = 0; mb < 8; ++mb) {
      const int row = mb * 16 + l15;
      const int ch  = (ks * 4 + quad) ^ (l15 & 7);
      bf16x8 ak = *(const bf16x8*)&Ksb[row * 64 + ch * 8];
      sacc[mb] = __builtin_amdgcn_mfma_f32_16x16x32_bf16(ak, bq[ks], sacc[mb], 0, 0, 0);
    }
  }
  __builtin_amdgcn_s_setprio(0);

  if (maskit) {
#pragma unroll
    for (int mb = 0; mb < 8; ++mb) {
      const int kb = k0 + mb * 16 + quad * 4;
#pragma unroll
      for (int r = 0; r < 4; ++r)
        if (kb + r > qrow) sacc[mb][r] = -1e30f;
    }
  }

  float mx = -1e30f;
#pragma unroll
  for (int mb = 0; mb < 8; ++mb)
    mx = fmaxf(mx, fmaxf(fmaxf(sacc[mb][0], sacc[mb][1]),
                         fmaxf(sacc[mb][2], sacc[mb][3])));
  mx = fmaxf(mx, __shfl_xor(mx, 16, 64));
  mx = fmaxf(mx, __shfl_xor(mx, 32, 64));

  float sum = 0.0f;
  bf16x4 pwv[8];
#pragma unroll
  for (int mb = 0; mb < 8; ++mb) {
    bf16x4 pw;
#pragma unroll
    for (int r = 0; r < 4; ++r) {
      const float p = __builtin_amdgcn_exp2f(sacc[mb][r] - mr);
      sum += p;
      pw[r] = (bf16)p;
    }
    pwv[mb] = pw;
  }
  sum += __shfl_xor(sum, 16, 64);
  sum += __shfl_xor(sum, 32, 64);

  __builtin_amdgcn_s_setprio(1);
#pragma unroll
  for (int mb = 0; mb < 8; ++mb) {
#pragma unroll
    for (int db = 0; db < 4; ++db) {
      const int vch = ((mb * 4 + quad) ^ (l15 & 7)) * 4;
      bf16x4 av = *(const bf16x4*)&Vtb[(db * 16 + l15) * 128 + vch];
      oacc[db] = pv_mfma(av, pwv[mb], oacc[db]);
    }
  }
  __builtin_amdgcn_s_setprio(0);

  lr += sum;
  if (!__all(mx <= mr + 8.0f)) {
    const float mnew  = fmaxf(mr, mx);
    const float alpha = __builtin_amdgcn_exp2f(mr - mnew);
    lr *= alpha;
#pragma unroll
    for (int db = 0; db < 4; ++db)
#pragma unroll
      for (int r = 0; r < 4; ++r) oacc[db][r] *= alpha;
    mr = mnew;
  }
}

// ---- fused variant: split loops, straight-line fused body ----
__global__ __launch_bounds__(256, 2) void attn_fused(
    const bf16* __restrict__ Q, const bf16* __restrict__ K,
    const bf16* __restrict__ V, bf16* __restrict__ O)
{
  __shared__ __align__(16) bf16 Ks[2][128 * 64];
  __shared__ __align__(16) bf16 Vt[2][64 * 128];

  ATTN_PROLOGUE();

  STAGE_K(0, 0);
  LOAD_V(0);
  WRITE_V(0);
  __syncthreads();

  float mrL = 0.0f, lrL = 0.0f, mrH = 0.0f, lrH = 0.0f;
  f32x4 oL[4] = {}, oH[4] = {};

  // ---- loop 1: it in [0, nl) — BOTH q-tiles active, straight-line ----
  // prefetch it+1 always legal: it+1 <= nl < nh.  H never masked here
  // (it <= nl-1 < nh-1); L masked at it == nl-1.
  for (int it = 0; it < nl; ++it) {
    const int c = it & 1;

    STAGE_K((it + 1) * 128, c ^ 1);
    LOAD_V((it + 1) * 128);

    // fused S^T = K Q^T: each ak b128 read feeds BOTH q-tiles
    f32x4 sH[8] = {}, sL[8] = {};
    __builtin_amdgcn_s_setprio(1);
#pragma unroll
    for (int ks = 0; ks < 2; ++ks) {
#pragma unroll
      for (int mb = 0; mb < 8; ++mb) {
        const int row = mb * 16 + l15;
        const int ch  = (ks * 4 + quad) ^ (l15 & 7);
        bf16x8 ak = *(const bf16x8*)&Ks[c][row * 64 + ch * 8];
        sH[mb] = __builtin_amdgcn_mfma_f32_16x16x32_bf16(ak, bqH[ks], sH[mb], 0, 0, 0);
        sL[mb] = __builtin_amdgcn_mfma_f32_16x16x32_bf16(ak, bqL[ks], sL[mb], 0, 0, 0);
      }
    }
    __builtin_amdgcn_s_setprio(0);

    bf16x4 pwH[8], pwL[8];
    float mxH = -1e30f, mxL = -1e30f;
    SMAX(sH, pwH, mrH, lrH, mxH, qrowH, false);
    SMAX(sL, pwL, mrL, lrL, mxL, qrowL, it == nl - 1);

    // fused O^T += V^T P^T: each av b64 read feeds BOTH q-tiles
    __builtin_amdgcn_s_setprio(1);
#pragma unroll
    for (int mb = 0; mb < 8; ++mb) {
#pragma unroll
      for (int db = 0; db < 4; ++db) {
        const int vch = ((mb * 4 + quad) ^ (l15 & 7)) * 4;
        bf16x4 av = *(const bf16x4*)&Vt[c][(db * 16 + l15) * 128 + vch];
        oH[db] = pv_mfma(av, pwH[mb], oH[db]);
        oL[db] = pv_mfma(av, pwL[mb], oL[db]);
      }
    }
    __builtin_amdgcn_s_setprio(0);

    FIXUP(mxH, mrH, lrH, oH);
    FIXUP(mxL, mrL, lrL, oL);

    WRITE_V(c ^ 1);
    __syncthreads();
  }

  // ---- loop 2: it in [nl, nh) — H only (proven single-tile step) ----
  for (int it = nl; it < nh; ++it) {
    const int c = it & 1;
    const bool pre = (it + 1 < nh);

    if (pre) {
      STAGE_K((it + 1) * 128, c ^ 1);
      LOAD_V((it + 1) * 128);
    }

    attn_tile_step(Ks[c], Vt[c], bqH, qrowH, it * 128, it == nh - 1,
                   mrH, lrH, oH, l15, quad);

    if (pre) {
      WRITE_V(c ^ 1);
      __syncthreads();
    }
  }

  ATTN_EPILOGUE();
}

// ---- safe variant: R10 proven (57.1 us, 88 VGPR) ----
__global__ __launch_bounds__(256, 2) void attn_safe(
    const bf16* __restrict__ Q, const bf16* __restrict__ K,
    const bf16* __restrict__ V, bf16* __restrict__ O)
{
  __shared__ __align__(16) bf16 Ks[2][128 * 64];
  __shared__ __align__(16) bf16 Vt[2][64 * 128];

  ATTN_PROLOGUE();

  STAGE_K(0, 0);
  LOAD_V(0);
  WRITE_V(0);
  __syncthreads();

  float mrL = 0.0f, lrL = 0.0f, mrH = 0.0f, lrH = 0.0f;
  f32x4 oL[4] = {}, oH[4] = {};

  for (int it = 0; it < nh; ++it) {
    const int c = it & 1;
    const bool pre = (it + 1 < nh);

    if (pre) {
      STAGE_K((it + 1) * 128, c ^ 1);
      LOAD_V((it + 1) * 128);
    }

    attn_tile_step(Ks[c], Vt[c], bqH, qrowH, it * 128, it == nh - 1,
                   mrH, lrH, oH, l15, quad);
    if (it < nl)
      attn_tile_step(Ks[c], Vt[c], bqL, qrowL, it * 128, it == nl - 1,
                     mrL, lrL, oL, l15, quad);

    if (pre) {
      WRITE_V(c ^ 1);
      __syncthreads();
    }
  }

  ATTN_EPILOGUE();
}

extern "C" void kernel_launch(void* const* d_in, const int* in_sizes, int n_in,
                              void* d_out, int out_size, void* d_ws, size_t ws_size,
                              hipStream_t stream) {
  const float* hs = (const float*)d_in[0];
  const float* Wq = (const float*)d_in[1]; const float* bq = (const float*)d_in[2];
  const float* Wk = (const float*)d_in[3]; const float* bk = (const float*)d_in[4];
  const float* Wv = (const float*)d_in[5]; const float* bv = (const float*)d_in[6];
  const float* Wo = (const float*)d_in[7]; const float* bo = (const float*)d_in[8];
  float* out = (float*)d_out;

  const size_t elems = (size_t)B_ * S_ * H_;   // 4,194,304
  const size_t wel   = (size_t)H_ * H_;        // 1,048,576
  // workspace (40 MB): [hsb | AO aliased 8MB][W bf16 8MB][Q 8][K 8][V 8]
  bf16* hsb = (bf16*)d_ws;      // read only by QKV GEMM
  bf16* AO  = hsb;              // written by attn (hsb dead by then)
  bf16* Wqb = hsb + elems;
  bf16* Wkb = Wqb + wel;
  bf16* Wvb = Wkb + wel;
  bf16* Wob = Wvb + wel;
  bf16* Qw  = Wob + wel;
  bf16* Kw  = Qw + elems;
  bf16* Vw  = Kw + elems;

  // one-time spill-canary check: use the fused attn only if it compiled
  // without scratch (localSizeBytes==0) and keeps 2 waves/SIMD (<=256 regs).
  static int use_fused = -1;
  if (use_fused < 0) {
    hipFuncAttributes fa;
    if (hipFuncGetAttributes(&fa, (const void*)attn_fused) == hipSuccess &&
        fa.localSizeBytes == 0 && fa.numRegs <= 256)
      use_fused = 1;
    else
      use_fused = 0;
  }

  cvt_f32_bf16<<<dim3(2048, 5), dim3(256), 0, stream>>>(
      hs, hsb, (int)elems, Wq, Wqb, Wk, Wkb, Wv, Wvb, Wo, Wob, (int)wel);

  const int M = B_ * S_;   // 4096
  const float QSCL = 0.125f * 1.44269504f;   // (1/sqrt(64)) * log2(e)

  gemm_qkv<<<dim3(H_ / 128, M / 128, 3), dim3(256), 0, stream>>>(
      hsb, Wqb, Wkb, Wvb, bq, bk, bv, Qw, Kw, Vw, QSCL, M, H_, H_);

  if (use_fused)
    attn_fused<<<dim3(512), dim3(256), 0, stream>>>(Qw, Kw, Vw, AO);
  else
    attn_safe<<<dim3(512), dim3(256), 0, stream>>>(Qw, Kw, Vw, AO);

  gemm_o_64<<<dim3(8, 64), dim3(256), 0, stream>>>(AO, Wob, bo, out);
}